// Round 1
// baseline (88.736 us; speedup 1.0000x reference)
//
#include <hip/hip_runtime.h>
#include <hip/hip_bf16.h>
#include <math.h>

// Problem constants (from reference setup_inputs)
#define NB 16384   // batch rows of logits
#define NC 4096    // classes / prototypes
#define ND 768     // prototype dim
// ws layout:
//   [0      .. 65536)  float nll[16384]
//   [65536  .. 69632)  float ic_part[1024]
//   [69632  .. 86016)  float t1[4096]      = (1-b_i)*||p_i||^2  (fp32 exact)
//   [86016  .. +6.29M) ushort P16[4096*768] bf16 prototypes
#define WS_NLL   0
#define WS_ICP   65536
#define WS_T1    69632
#define WS_P16   86016

typedef __bf16 bf16x8 __attribute__((ext_vector_type(8)));
typedef float  f32x4  __attribute__((ext_vector_type(4)));

__device__ __forceinline__ unsigned short f2bf(float f) {
    return __builtin_bit_cast(unsigned short, __float2bfloat16(f));
}

// ---------------- prep: per-row ||p||^2 (fp32) + bf16 convert ----------------
template<bool PRECONV>
__global__ __launch_bounds__(256) void prep_kernel(const float* __restrict__ prot,
                                                   const float* __restrict__ bnd,
                                                   float* __restrict__ t1,
                                                   unsigned short* __restrict__ P16) {
    int w = threadIdx.x >> 6;
    int lane = threadIdx.x & 63;
    int row = blockIdx.x * 4 + w;
    const float4* rp = reinterpret_cast<const float4*>(prot + (size_t)row * ND);
    float ss = 0.f;
#pragma unroll
    for (int it = 0; it < 3; ++it) {
        int idx = it * 64 + lane;            // 192 float4 per row
        float4 v = rp[idx];
        ss += v.x * v.x + v.y * v.y + v.z * v.z + v.w * v.w;
        if (PRECONV) {
            ushort4 h;
            h.x = f2bf(v.x); h.y = f2bf(v.y); h.z = f2bf(v.z); h.w = f2bf(v.w);
            *reinterpret_cast<ushort4*>(P16 + (size_t)row * ND + idx * 4) = h;
        }
    }
#pragma unroll
    for (int off = 32; off; off >>= 1) ss += __shfl_xor(ss, off);
    if (lane == 0) t1[row] = (1.f - bnd[row]) * ss;
}

// ---------------- cross-entropy: one block per row ----------------
__global__ __launch_bounds__(256) void ce_kernel(const float* __restrict__ logits,
                                                 const int* __restrict__ targets,
                                                 float* __restrict__ nll) {
    int row = blockIdx.x;
    int tid = threadIdx.x;
    const float4* rp = reinterpret_cast<const float4*>(logits + (size_t)row * NC);
    float4 v[4];
#pragma unroll
    for (int i = 0; i < 4; ++i) v[i] = rp[tid + 256 * i];   // 1024 float4 per row
    float m = -3.4e38f;
#pragma unroll
    for (int i = 0; i < 4; ++i)
        m = fmaxf(m, fmaxf(fmaxf(v[i].x, v[i].y), fmaxf(v[i].z, v[i].w)));
    float s = 0.f;
#pragma unroll
    for (int i = 0; i < 4; ++i)
        s += __expf(v[i].x - m) + __expf(v[i].y - m) + __expf(v[i].z - m) + __expf(v[i].w - m);
    // wave-level (m,s) merge
#pragma unroll
    for (int off = 32; off; off >>= 1) {
        float mo = __shfl_xor(m, off);
        float so = __shfl_xor(s, off);
        float mn = fmaxf(m, mo);
        s = s * __expf(m - mn) + so * __expf(mo - mn);
        m = mn;
    }
    __shared__ float smx[4], ssm[4];
    int w = tid >> 6, lane = tid & 63;
    if (lane == 0) { smx[w] = m; ssm[w] = s; }
    __syncthreads();
    if (tid == 0) {
        float M = smx[0], S = ssm[0];
#pragma unroll
        for (int i = 1; i < 4; ++i) {
            float mn = fmaxf(M, smx[i]);
            S = S * __expf(M - mn) + ssm[i] * __expf(smx[i] - mn);
            M = mn;
        }
        int t = targets[row];
        float xt = logits[(size_t)row * NC + t];
        nll[row] = M + __logf(S) - xt;
    }
}

// ---------------- fused Gram + constraint + partial reduce ----------------
// 128x128 tile per block, 4 waves (2x2), each wave 64x64 via 4x4 frags of 16x16x32.
template<bool PRECONV>
__global__ __launch_bounds__(256) void ic_kernel(const unsigned short* __restrict__ P16,
                                                 const float* __restrict__ prot,
                                                 const float* __restrict__ bnd,
                                                 const float* __restrict__ t1,
                                                 float* __restrict__ ic_part) {
    __shared__ __bf16 As[128][72];   // 64 + 8 pad (2-way bank alias only)
    __shared__ __bf16 Bs[128][72];
    int tid = threadIdx.x;
    int bi = blockIdx.x >> 5, bj = blockIdx.x & 31;
    int row0 = bi * 128, col0 = bj * 128;
    int lane = tid & 63, w = tid >> 6;
    int fr = lane & 15, fq = lane >> 4;
    int wrow = (w >> 1) * 64, wcol = (w & 1) * 64;

    f32x4 acc[4][4];
#pragma unroll
    for (int mi = 0; mi < 4; ++mi)
#pragma unroll
        for (int nj = 0; nj < 4; ++nj) acc[mi][nj] = (f32x4){0.f, 0.f, 0.f, 0.f};

    for (int kt = 0; kt < ND / 64; ++kt) {
        if (PRECONV) {
#pragma unroll
            for (int s2 = 0; s2 < 4; ++s2) {
                int c = tid + 256 * s2;          // 1024 chunks of 8 bf16 per tile
                int r = c >> 3, k8 = c & 7;
                uint4 va = *reinterpret_cast<const uint4*>(P16 + (size_t)(row0 + r) * ND + kt * 64 + k8 * 8);
                *reinterpret_cast<uint4*>(&As[r][k8 * 8]) = va;
                uint4 vb = *reinterpret_cast<const uint4*>(P16 + (size_t)(col0 + r) * ND + kt * 64 + k8 * 8);
                *reinterpret_cast<uint4*>(&Bs[r][k8 * 8]) = vb;
            }
        } else {
#pragma unroll
            for (int s2 = 0; s2 < 8; ++s2) {
                int c = tid + 256 * s2;          // 2048 chunks of 4 floats per tile
                int r = c >> 4, k4 = c & 15;
                float4 va = *reinterpret_cast<const float4*>(prot + (size_t)(row0 + r) * ND + kt * 64 + k4 * 4);
                ushort4 ha; ha.x = f2bf(va.x); ha.y = f2bf(va.y); ha.z = f2bf(va.z); ha.w = f2bf(va.w);
                *reinterpret_cast<ushort4*>(&As[r][k4 * 4]) = ha;
                float4 vb = *reinterpret_cast<const float4*>(prot + (size_t)(col0 + r) * ND + kt * 64 + k4 * 4);
                ushort4 hb; hb.x = f2bf(vb.x); hb.y = f2bf(vb.y); hb.z = f2bf(vb.z); hb.w = f2bf(vb.w);
                *reinterpret_cast<ushort4*>(&Bs[r][k4 * 4]) = hb;
            }
        }
        __syncthreads();
#pragma unroll
        for (int ks = 0; ks < 64; ks += 32) {
            bf16x8 af[4], bfv[4];
#pragma unroll
            for (int mi = 0; mi < 4; ++mi)
                af[mi] = *reinterpret_cast<const bf16x8*>(&As[wrow + mi * 16 + fr][ks + fq * 8]);
#pragma unroll
            for (int nj = 0; nj < 4; ++nj)
                bfv[nj] = *reinterpret_cast<const bf16x8*>(&Bs[wcol + nj * 16 + fr][ks + fq * 8]);
#pragma unroll
            for (int mi = 0; mi < 4; ++mi)
#pragma unroll
                for (int nj = 0; nj < 4; ++nj)
                    acc[mi][nj] = __builtin_amdgcn_mfma_f32_16x16x32_bf16(af[mi], bfv[nj], acc[mi][nj], 0, 0, 0);
        }
        __syncthreads();
    }

    // epilogue: constraint = t1[i] + (b_j - 1) * G[i,j], relu, skip diag, reduce
    float t1r[16];
#pragma unroll
    for (int mi = 0; mi < 4; ++mi)
#pragma unroll
        for (int e = 0; e < 4; ++e)
            t1r[mi * 4 + e] = t1[row0 + wrow + mi * 16 + fq * 4 + e];
    float cj[4];
#pragma unroll
    for (int nj = 0; nj < 4; ++nj) cj[nj] = bnd[col0 + wcol + nj * 16 + fr] - 1.f;

    float sum = 0.f;
#pragma unroll
    for (int mi = 0; mi < 4; ++mi) {
#pragma unroll
        for (int nj = 0; nj < 4; ++nj) {
#pragma unroll
            for (int e = 0; e < 4; ++e) {
                int i = row0 + wrow + mi * 16 + fq * 4 + e;
                int j = col0 + wcol + nj * 16 + fr;
                float con = t1r[mi * 4 + e] + cj[nj] * acc[mi][nj][e];
                if (i != j) sum += fmaxf(con, 0.f);
            }
        }
    }
#pragma unroll
    for (int off = 32; off; off >>= 1) sum += __shfl_xor(sum, off);
    __shared__ float bs[4];
    if (lane == 0) bs[w] = sum;
    __syncthreads();
    if (tid == 0) ic_part[blockIdx.x] = bs[0] + bs[1] + bs[2] + bs[3];
}

// ---------------- finalize: reduce nll + ic partials, write 3 outputs ----------------
__global__ __launch_bounds__(1024) void fin_kernel(const float* __restrict__ nll,
                                                   const float* __restrict__ icp,
                                                   float* __restrict__ out) {
    int tid = threadIdx.x;
    double s = 0.0;
    for (int i = tid; i < NB; i += 1024) s += (double)nll[i];
    double s2 = (double)icp[tid];   // exactly 1024 partials
#pragma unroll
    for (int off = 32; off; off >>= 1) {
        s  += __shfl_xor(s, off);
        s2 += __shfl_xor(s2, off);
    }
    __shared__ double sm[16], sm2[16];
    int w = tid >> 6, lane = tid & 63;
    if (lane == 0) { sm[w] = s; sm2[w] = s2; }
    __syncthreads();
    if (tid == 0) {
        double a = 0.0, b = 0.0;
        for (int i = 0; i < 16; ++i) { a += sm[i]; b += sm2[i]; }
        double cls = a / (double)NB;
        double ic  = b / ((double)NC * (double)(NC - 1));
        out[0] = (float)(cls + 0.05 * ic);
        out[1] = (float)cls;
        out[2] = (float)ic;
    }
}

extern "C" void kernel_launch(void* const* d_in, const int* in_sizes, int n_in,
                              void* d_out, int out_size, void* d_ws, size_t ws_size,
                              hipStream_t stream) {
    const float* logits  = (const float*)d_in[0];
    const int*   targets = (const int*)d_in[1];
    const float* prot    = (const float*)d_in[2];
    const float* bnd     = (const float*)d_in[3];
    float* out = (float*)d_out;
    char* ws = (char*)d_ws;
    float* nll = (float*)(ws + WS_NLL);
    float* icp = (float*)(ws + WS_ICP);
    float* t1  = (float*)(ws + WS_T1);
    unsigned short* P16 = (unsigned short*)(ws + WS_P16);
    bool pre = ws_size >= (size_t)WS_P16 + 2ull * NC * ND;

    ce_kernel<<<NB, 256, 0, stream>>>(logits, targets, nll);
    if (pre) {
        prep_kernel<true><<<NC / 4, 256, 0, stream>>>(prot, bnd, t1, P16);
        ic_kernel<true><<<1024, 256, 0, stream>>>(P16, prot, bnd, t1, icp);
    } else {
        prep_kernel<false><<<NC / 4, 256, 0, stream>>>(prot, bnd, t1, nullptr);
        ic_kernel<false><<<1024, 256, 0, stream>>>(nullptr, prot, bnd, t1, icp);
    }
    fin_kernel<<<1, 1024, 0, stream>>>(nll, icp, out);
}